// Round 16
// baseline (204.202 us; speedup 1.0000x reference)
//
#include <hip/hip_runtime.h>

typedef unsigned short u16;
typedef unsigned int u32;
typedef __bf16 bf16x8 __attribute__((ext_vector_type(8)));
typedef float f32x4 __attribute__((ext_vector_type(4)));
typedef float f32x16 __attribute__((ext_vector_type(16)));
typedef u32 u32x4 __attribute__((ext_vector_type(4)));

// ---------- helpers (native casts -> compiler emits v_cvt_pk_bf16_f32) ----------
__device__ __forceinline__ u16 bfu(float x) {
  union { __bf16 h; u16 u; } z; z.h = (__bf16)x; return z.u;
}
__device__ __forceinline__ float b2f(u16 u) {
  union { u32 u; float f; } z; z.u = ((u32)u) << 16; return z.f;
}
__device__ __forceinline__ u32 pk2(float a, float b) {
  union { __bf16 h[2]; u32 u; } z;
  z.h[0] = (__bf16)a; z.h[1] = (__bf16)b;
  return z.u;
}
__device__ __forceinline__ void gl_lds16(const u16* g, u16* l) {
  __builtin_amdgcn_global_load_lds((const __attribute__((address_space(1))) void*)g,
                                   (__attribute__((address_space(3))) void*)l, 16, 0, 0);
}

// ---------- fp32 -> bf16 elementwise (8 elems/thread) ----------
__global__ __launch_bounds__(256) void cvt_bf16(const float* __restrict__ src, u16* __restrict__ dst, int n8) {
  int i = blockIdx.x * 256 + threadIdx.x;
  if (i >= n8) return;
  const float4* s4 = (const float4*)src;
  float4 a = s4[2 * i], b = s4[2 * i + 1];
  u32x4 o;
  o[0] = pk2(a.x, a.y); o[1] = pk2(a.z, a.w);
  o[2] = pk2(b.x, b.y); o[3] = pk2(b.z, b.w);
  ((u32x4*)dst)[i] = o;
}

// ---------- paired tiled transpose + convert: z selects (s0->d0) or (s1->d1) ----------
__global__ void transpose_cvt2(const float* __restrict__ s0, u16* __restrict__ d0,
                               const float* __restrict__ s1, u16* __restrict__ d1,
                               int R, int C) {
  __shared__ float tile[32][33];
  const float* src = blockIdx.z ? s1 : s0;
  u16* dst = blockIdx.z ? d1 : d0;
  const int c0 = blockIdx.x * 32, r0 = blockIdx.y * 32;
  const int tx = threadIdx.x, ty = threadIdx.y;
#pragma unroll
  for (int i = 0; i < 4; ++i)
    tile[ty + i * 8][tx] = src[(size_t)(r0 + ty + i * 8) * C + c0 + tx];
  __syncthreads();
#pragma unroll
  for (int i = 0; i < 4; ++i)
    dst[(size_t)(c0 + ty + i * 8) * R + r0 + tx] = bfu(tile[tx][ty + i * 8]);
}

// ---------- V slice of bf16 QKV: add bias, transpose to Vt[B][128][2048] bf16 ----------
__global__ void transpose_v(const u16* __restrict__ QKV, const float* __restrict__ bv, u16* __restrict__ Vt) {
  __shared__ float tile[32][33];
  const int t0 = blockIdx.x * 32, d0 = blockIdx.y * 32, b = blockIdx.z;
  const int tx = threadIdx.x, ty = threadIdx.y;
#pragma unroll
  for (int i = 0; i < 4; ++i)
    tile[ty + i * 8][tx] = b2f(QKV[(size_t)(b * 2048 + t0 + ty + i * 8) * 2304 + 2176 + d0 + tx]) + bv[d0 + tx];
  __syncthreads();
#pragma unroll
  for (int i = 0; i < 4; ++i)
    Vt[(size_t)b * 262144 + (size_t)(d0 + ty + i * 8) * 2048 + t0 + tx] = bfu(tile[tx][ty + i * 8]);
}

// ---------- RoPE + bias from bf16 QKV: Qb pre-scaled by log2(e)/sqrt(D) ----------
__global__ __launch_bounds__(256) void rope_qk(const u16* __restrict__ QKV, const float* __restrict__ bq,
                                               const float* __restrict__ bk,
                                               u16* __restrict__ Qb, u16* __restrict__ Kb) {
  const int row = blockIdx.x;          // b*2048 + t
  const int b = row >> 11, t = row & 2047;
  const int tid = threadIdx.x;
  const u16* qrow = QKV + (size_t)row * 2304;
  const float scale = 0.1275173862437171f;    // log2(e)/sqrt(128)
  const float nl2 = -0.20762050593046f;       // -log2(10000)/64
#pragma unroll
  for (int it = 0; it < 4; ++it) {
    int idx = tid + it * 256;          // 0..1023 : h*64 + j
    int h = idx >> 6, j = idx & 63;
    float q0 = b2f(qrow[h * 128 + j]) + bq[h * 128 + j];
    float q1 = b2f(qrow[h * 128 + j + 64]) + bq[h * 128 + j + 64];
    float ang = (float)t * exp2f((float)j * nl2);
    float s, c;
    __sincosf(ang, &s, &c);
    size_t o = ((size_t)((b * 16 + h) * 2048 + t)) * 128 + j;
    Qb[o]      = bfu((q0 * c - q1 * s) * scale);
    Qb[o + 64] = bfu((q1 * c + q0 * s) * scale);
  }
  if (tid < 64) {
    int j = tid;
    float k0 = b2f(qrow[2048 + j]) + bk[j];
    float k1 = b2f(qrow[2048 + j + 64]) + bk[j + 64];
    float ang = (float)t * exp2f((float)j * nl2);
    float s, c;
    __sincosf(ang, &s, &c);
    size_t o = (size_t)row * 128 + j;
    Kb[o]      = bfu(k0 * c - k1 * s);
    Kb[o + 64] = bfu(k1 * c + k0 * s);
  }
}

// ---------- GEMM: C[M][N] = A[M][K](bf16) @ Bt[N][K](bf16)^T (+bias), fp32 or bf16 out ----------
// 128x128 tile, BK=128 (16 K-steps; 64 MFMA/wave/step), 4 waves 2x2.
// LDS [128][128]u16 (64KB) with XOR-chunk swizzle (rule-21: linear LDS dest, pre-swizzled
// GLOBAL source chunk, swizzled read offset) -> ds_read_b128 2-way conflict (free, m136).
// XCD-chunked block swizzle over NTL n-tiles.
template <bool BIAS, int NTL, bool OUT16>
__global__ __launch_bounds__(256) void gemm_bt(const u16* __restrict__ A, const u16* __restrict__ Bt,
                                               const float* __restrict__ bias, float* __restrict__ C,
                                               int M, int N, int K) {
  const int lin = blockIdx.x;
  const int xcd = lin & 7, idx = lin >> 3;
  constexpr int HALF = NTL / 2;                 // 9 or 8
  const int ly = idx / HALF, lx = idx - ly * HALF;   // ly 0..7
  const int my = (xcd >> 1) * 8 + ly;           // m-tile 0..31
  const int nx = (xcd & 1) * HALF + lx;         // n-tile 0..NTL-1
  const int n0 = nx * 128, m0 = my * 128;
  const int tid = threadIdx.x, lane = tid & 63;
  const int wid = tid >> 6, wr = wid >> 1, wc = wid & 1;
  __shared__ __align__(16) u16 As[128 * 128];   // 32 KB
  __shared__ __align__(16) u16 Bs[128 * 128];   // 32 KB
  f32x4 acc[4][4];
#pragma unroll
  for (int i = 0; i < 4; ++i)
#pragma unroll
    for (int j = 0; j < 4; ++j)
#pragma unroll
      for (int rr = 0; rr < 4; ++rr) acc[i][j][rr] = 0.f;

  // staging: tile = 128 rows x 16 chunks of 16B = 2048 slots; thread covers 8
  int srow[8], scol[8];
#pragma unroll
  for (int i = 0; i < 8; ++i) {
    const int c = tid + i * 256;
    srow[i] = c >> 4;                                   // LDS row 0..127
    scol[i] = (((c & 15) ^ (srow[i] & 15)) << 3);       // swizzled source chunk (u16 units)
  }
  const int r = lane & 15, g = lane >> 4;
  // swizzled read offsets: fragment rows have row&15 == r
  int koff[4];
#pragma unroll
  for (int s = 0; s < 4; ++s) koff[s] = (((s * 4 + g) ^ r) << 3);

  const int NT = K >> 7;                        // 16 K-steps of 128
  for (int t = 0; t < NT; ++t) {
    const int k0 = t << 7;
#pragma unroll
    for (int i = 0; i < 8; ++i)
      gl_lds16(A + (size_t)(m0 + srow[i]) * K + k0 + scol[i], As + (tid + i * 256) * 8);
#pragma unroll
    for (int i = 0; i < 8; ++i)
      gl_lds16(Bt + (size_t)(n0 + srow[i]) * K + k0 + scol[i], Bs + (tid + i * 256) * 8);
    __syncthreads();
#pragma unroll
    for (int s = 0; s < 4; ++s) {
      bf16x8 af[4], bfr[4];
#pragma unroll
      for (int mi = 0; mi < 4; ++mi)
        af[mi] = *reinterpret_cast<const bf16x8*>(&As[(wr * 64 + mi * 16 + r) * 128 + koff[s]]);
#pragma unroll
      for (int ni = 0; ni < 4; ++ni)
        bfr[ni] = *reinterpret_cast<const bf16x8*>(&Bs[(wc * 64 + ni * 16 + r) * 128 + koff[s]]);
#pragma unroll
      for (int mi = 0; mi < 4; ++mi)
#pragma unroll
        for (int ni = 0; ni < 4; ++ni)
          acc[mi][ni] = __builtin_amdgcn_mfma_f32_16x16x32_bf16(af[mi], bfr[ni], acc[mi][ni], 0, 0, 0);
    }
    __syncthreads();
  }
#pragma unroll
  for (int mi = 0; mi < 4; ++mi)
#pragma unroll
    for (int ni = 0; ni < 4; ++ni) {
      int col = n0 + wc * 64 + ni * 16 + r;
      float bia = BIAS ? bias[col] : 0.f;
#pragma unroll
      for (int reg = 0; reg < 4; ++reg) {
        int row = m0 + wr * 64 + mi * 16 + g * 4 + reg;
        if constexpr (OUT16) {
          ((u16*)C)[(size_t)row * N + col] = bfu(acc[mi][ni][reg] + bia);
        } else {
          C[(size_t)row * N + col] = acc[mi][ni][reg] + bia;
        }
      }
    }
}

// ---------- flash attention (causal, MQA), LDS-staged double-buffered K/V (R12-validated) ----------
__global__ __launch_bounds__(256, 2) void attn_kernel(const u16* __restrict__ Qb, const u16* __restrict__ Kb,
                                                      const u16* __restrict__ Vt, u16* __restrict__ Ob) {
  const int bid = blockIdx.x;
  const int grp = bid >> 5;                       // 0..15
  const int chunk = (bid < 256) ? (15 - grp) : (grp - 8);
  const int bh = bid & 31, h = bh & 15, b = bh >> 4;
  const int tid = threadIdx.x, wid = tid >> 6, lane = tid & 63;
  const int l31 = lane & 31, hf = lane >> 5;

  __shared__ __align__(16) u16 smem[32768];       // 64KB
  u16* Ksb = smem;                                // [2][8192]
  u16* Vsb = smem + 16384;                        // [2][8192]

  const u16* Kbase = Kb + (size_t)b * 2048 * 128;
  const u16* Vbase = Vt + (size_t)b * 128 * 2048;

  int krow[4], kcol[4], vrow[4], vcol[4];
#pragma unroll
  for (int i = 0; i < 4; ++i) {
    const int seg = wid * 4 + i;
    const int r = seg * 4 + (lane >> 4);                 // K tile row (kv)
    krow[i] = r; kcol[i] = (((lane & 15) ^ (r & 15)) << 3);
    const int d = seg * 8 + (lane >> 3);                 // V tile row (d)
    vrow[i] = d; vcol[i] = (((lane & 7) ^ (d & 7)) << 3);
  }
  const int ldsoff = wid * 2048 + lane * 8;              // u16 units

#define STAGE(buf, kvb_) do {                                                              \
    _Pragma("unroll") for (int i_ = 0; i_ < 4; ++i_)                                       \
      gl_lds16(Kbase + (size_t)((kvb_) + krow[i_]) * 128 + kcol[i_],                       \
               &Ksb[(buf) * 8192 + ldsoff + i_ * 512]);                                    \
    _Pragma("unroll") for (int i_ = 0; i_ < 4; ++i_)                                       \
      gl_lds16(Vbase + (size_t)vrow[i_] * 2048 + (kvb_) + vcol[i_],                        \
               &Vsb[(buf) * 8192 + ldsoff + i_ * 512]);                                    \
  } while (0)

  const int xk16 = l31 & 15;   // K read swizzle
  const int xk8 = l31 & 7;     // V read swizzle

  const int cb = chunk * 128;
  const int qw = cb + wid * 32;                          // this wave's q-tile base
  const u16* qptr = Qb + ((size_t)((b * 16 + h) * 2048 + qw + l31)) * 128;
  bf16x8 qf[8];
#pragma unroll
  for (int c = 0; c < 8; ++c)
    qf[c] = *reinterpret_cast<const bf16x8*>(qptr + c * 16 + hf * 8);

  f32x16 ot[4];
#pragma unroll
  for (int dt = 0; dt < 4; ++dt)
#pragma unroll
    for (int rr = 0; rr < 16; ++rr) ot[dt][rr] = 0.f;
  float m = -1e30f, lsum = 0.f;

  const int nkv = 2 * chunk + 2;
  STAGE(0, 0);
  for (int it = 0; it < nkv; ++it) {
    const int kvb = it << 6, cur = it & 1;
    if (it + 1 < nkv) {
      STAGE(cur ^ 1, kvb + 64);
      asm volatile("s_waitcnt vmcnt(8)" ::: "memory");
    } else {
      asm volatile("s_waitcnt vmcnt(0)" ::: "memory");
    }
    __builtin_amdgcn_s_barrier();

    if (kvb <= qw) {
      const u16* ks = Ksb + cur * 8192;
      const u16* vs = Vsb + cur * 8192;
      f32x16 st0, st1;
#pragma unroll
      for (int rr = 0; rr < 16; ++rr) { st0[rr] = 0.f; st1[rr] = -1e30f; }
      const u16* ksr0 = ks + l31 * 128;
#pragma unroll
      for (int c = 0; c < 8; ++c) {
        bf16x8 kf = *reinterpret_cast<const bf16x8*>(ksr0 + (((2 * c + hf) ^ xk16) << 3));
        st0 = __builtin_amdgcn_mfma_f32_32x32x16_bf16(kf, qf[c], st0, 0, 0, 0);
      }
      const bool a1 = (kvb + 32 <= qw);
      if (a1) {
#pragma unroll
        for (int rr = 0; rr < 16; ++rr) st1[rr] = 0.f;
        const u16* ksr1 = ks + (32 + l31) * 128;
#pragma unroll
        for (int c = 0; c < 8; ++c) {
          bf16x8 kf = *reinterpret_cast<const bf16x8*>(ksr1 + (((2 * c + hf) ^ xk16) << 3));
          st1 = __builtin_amdgcn_mfma_f32_32x32x16_bf16(kf, qf[c], st1, 0, 0, 0);
        }
        if (kvb + 32 == qw) {
#pragma unroll
          for (int rr = 0; rr < 16; ++rr) {
            int kvl = (rr & 3) + 8 * (rr >> 2) + 4 * hf;
            if (kvl > l31) st1[rr] = -1e30f;
          }
        }
      }
      if (kvb == qw) {
#pragma unroll
        for (int rr = 0; rr < 16; ++rr) {
          int kvl = (rr & 3) + 8 * (rr >> 2) + 4 * hf;
          if (kvl > l31) st0[rr] = -1e30f;
        }
      }

      float tmax = st0[0];
#pragma unroll
      for (int rr = 1; rr < 16; ++rr) tmax = fmaxf(tmax, st0[rr]);
#pragma unroll
      for (int rr = 0; rr < 16; ++rr) tmax = fmaxf(tmax, st1[rr]);
      tmax = fmaxf(tmax, __shfl_xor(tmax, 32, 64));
      if (!__all(tmax - m <= 8.f)) {
        const float mnew = fmaxf(m, tmax);
        const float alpha = exp2f(m - mnew);
        lsum *= alpha;
#pragma unroll
        for (int dt = 0; dt < 4; ++dt)
#pragma unroll
          for (int rr = 0; rr < 16; ++rr) ot[dt][rr] *= alpha;
        m = mnew;
      }
      float rsum = 0.f;
#pragma unroll
      for (int rr = 0; rr < 16; ++rr) { st0[rr] = exp2f(st0[rr] - m); rsum += st0[rr]; }
#pragma unroll
      for (int rr = 0; rr < 16; ++rr) { st1[rr] = exp2f(st1[rr] - m); rsum += st1[rr]; }
      rsum += __shfl_xor(rsum, 32, 64);
      lsum += rsum;

#pragma unroll
      for (int n = 0; n < 2; ++n) {
        if (n == 1 && !a1) break;
        const f32x16& pp = n ? st1 : st0;
#pragma unroll
        for (int s = 0; s < 2; ++s) {
          u32 a0p = pk2(pp[8 * s + 0], pp[8 * s + 1]);
          u32 a1p = pk2(pp[8 * s + 2], pp[8 * s + 3]);
          u32 b0p = pk2(pp[8 * s + 4], pp[8 * s + 5]);
          u32 b1p = pk2(pp[8 * s + 6], pp[8 * s + 7]);
          u32 k0 = hf ? b0p : a0p, k1 = hf ? b1p : a1p;
          u32 sd0 = hf ? a0p : b0p, sd1 = hf ? a1p : b1p;
          u32 r0 = (u32)__shfl_xor((int)sd0, 32, 64);
          u32 r1 = (u32)__shfl_xor((int)sd1, 32, 64);
          u32x4 pw;
          pw[0] = hf ? r0 : k0; pw[1] = hf ? r1 : k1;
          pw[2] = hf ? k0 : r0; pw[3] = hf ? k1 : r1;
          bf16x8 pb = __builtin_bit_cast(bf16x8, pw);
          const int cc = n * 4 + s * 2 + hf;
#pragma unroll
          for (int dt = 0; dt < 4; ++dt) {
            bf16x8 vf = *reinterpret_cast<const bf16x8*>(
                &vs[(dt * 32 + l31) * 64 + ((cc ^ xk8) << 3)]);
            ot[dt] = __builtin_amdgcn_mfma_f32_32x32x16_bf16(vf, pb, ot[dt], 0, 0, 0);
          }
        }
      }
    }
    __builtin_amdgcn_s_barrier();
  }

  // epilogue: normalize, LDS transpose (overlaid on K/V buffers), coalesced bf16 stores
  u16* myt = smem + wid * (32 * 136);
  const float inv = 1.f / lsum;
#pragma unroll
  for (int dt = 0; dt < 4; ++dt)
#pragma unroll
    for (int rq = 0; rq < 4; ++rq) {
      int d = dt * 32 + 8 * rq + 4 * hf;
      u32 lo = pk2(ot[dt][rq * 4 + 0] * inv, ot[dt][rq * 4 + 1] * inv);
      u32 hi = pk2(ot[dt][rq * 4 + 2] * inv, ot[dt][rq * 4 + 3] * inv);
      u32* dstp = (u32*)&myt[l31 * 136 + d];
      dstp[0] = lo; dstp[1] = hi;
    }
  __syncthreads();
  const size_t outbase = ((size_t)(b * 2048 + qw)) * 2048 + h * 128;
#pragma unroll
  for (int i = 0; i < 8; ++i) {
    int chunk2 = i * 64 + lane;
    int row = chunk2 >> 4, c16 = chunk2 & 15;
    u32x4 v = *reinterpret_cast<const u32x4*>(&myt[row * 136 + c16 * 8]);
    *reinterpret_cast<u32x4*>(Ob + outbase + (size_t)row * 2048 + c16 * 8) = v;
  }
#undef STAGE
}

// ---------- launch ----------
extern "C" void kernel_launch(void* const* d_in, const int* in_sizes, int n_in,
                              void* d_out, int out_size, void* d_ws, size_t ws_size,
                              hipStream_t stream) {
  const float* x  = (const float*)d_in[0];
  // d_in[1] = attn_mask (causal tril; applied analytically)
  const float* Wq = (const float*)d_in[2];
  const float* bq = (const float*)d_in[3];
  const float* Wk = (const float*)d_in[4];
  const float* bk = (const float*)d_in[5];
  const float* Wv = (const float*)d_in[6];
  const float* bv = (const float*)d_in[7];
  const float* Wo = (const float*)d_in[8];
  const float* bo = (const float*)d_in[9];

  char* ws = (char*)d_ws;
  u16*  xb    = (u16*)ws;   ws += (size_t)4096 * 2048 * 2;   // x bf16
  u16*  WqkvT = (u16*)ws;   ws += (size_t)2304 * 2048 * 2;   // [Wq|Wk|Wv]^T bf16
  u16*  WoT   = (u16*)ws;   ws += (size_t)2048 * 2048 * 2;   // Wo^T bf16
  u16*  QKV16 = (u16*)ws;   ws += (size_t)4096 * 2304 * 2;   // projections bf16
  u16*  Qb    = (u16*)ws;   ws += (size_t)2 * 16 * 2048 * 128 * 2; // [B,H,T,D] (RoPE'd, exp2-scaled)
  u16*  Kb    = (u16*)ws;   ws += (size_t)2 * 2048 * 128 * 2;      // [B,T,D] (RoPE'd)
  u16*  Vt    = (u16*)ws;   ws += (size_t)2 * 128 * 2048 * 2;      // [B,D,T]
  u16*  Ob    = (u16*)ws;   ws += (size_t)4096 * 2048 * 2;         // attn out bf16 [B*T][H*D]

  dim3 tb(32, 8);
  cvt_bf16<<<4096, 256, 0, stream>>>(x, xb, 1048576);
  transpose_cvt2<<<dim3(64, 64, 2), tb, 0, stream>>>(Wq, WqkvT, Wo, WoT, 2048, 2048);
  transpose_cvt2<<<dim3(4, 64, 2), tb, 0, stream>>>(Wk, WqkvT + (size_t)2048 * 2048,
                                                    Wv, WqkvT + (size_t)2176 * 2048, 2048, 128);

  gemm_bt<false, 18, true><<<576, 256, 0, stream>>>(xb, WqkvT, nullptr, (float*)QKV16, 4096, 2304, 2048);
  rope_qk<<<4096, 256, 0, stream>>>(QKV16, bq, bk, Qb, Kb);
  transpose_v<<<dim3(64, 4, 2), tb, 0, stream>>>(QKV16, bv, Vt);
  attn_kernel<<<512, 256, 0, stream>>>(Qb, Kb, Vt, Ob);
  gemm_bt<true, 16, false><<<512, 256, 0, stream>>>(Ob, WoT, bo, (float*)d_out, 4096, 2048, 2048);
}

// Round 17
// 192.558 us; speedup vs baseline: 1.0605x; 1.0605x over previous
//
#include <hip/hip_runtime.h>

typedef unsigned short u16;
typedef unsigned int u32;
typedef __bf16 bf16x8 __attribute__((ext_vector_type(8)));
typedef float f32x4 __attribute__((ext_vector_type(4)));
typedef float f32x16 __attribute__((ext_vector_type(16)));
typedef u32 u32x4 __attribute__((ext_vector_type(4)));

// ---------- helpers (native casts -> compiler emits v_cvt_pk_bf16_f32) ----------
__device__ __forceinline__ u16 bfu(float x) {
  union { __bf16 h; u16 u; } z; z.h = (__bf16)x; return z.u;
}
__device__ __forceinline__ float b2f(u16 u) {
  union { u32 u; float f; } z; z.u = ((u32)u) << 16; return z.f;
}
__device__ __forceinline__ u32 pk2(float a, float b) {
  union { __bf16 h[2]; u32 u; } z;
  z.h[0] = (__bf16)a; z.h[1] = (__bf16)b;
  return z.u;
}
__device__ __forceinline__ void gl_lds16(const u16* g, u16* l) {
  __builtin_amdgcn_global_load_lds((const __attribute__((address_space(1))) void*)g,
                                   (__attribute__((address_space(3))) void*)l, 16, 0, 0);
}

// ---------- fp32 -> bf16 elementwise (8 elems/thread) ----------
__global__ __launch_bounds__(256) void cvt_bf16(const float* __restrict__ src, u16* __restrict__ dst, int n8) {
  int i = blockIdx.x * 256 + threadIdx.x;
  if (i >= n8) return;
  const float4* s4 = (const float4*)src;
  float4 a = s4[2 * i], b = s4[2 * i + 1];
  u32x4 o;
  o[0] = pk2(a.x, a.y); o[1] = pk2(a.z, a.w);
  o[2] = pk2(b.x, b.y); o[3] = pk2(b.z, b.w);
  ((u32x4*)dst)[i] = o;
}

// ---------- paired tiled transpose + convert: z selects (s0->d0) or (s1->d1) ----------
__global__ void transpose_cvt2(const float* __restrict__ s0, u16* __restrict__ d0,
                               const float* __restrict__ s1, u16* __restrict__ d1,
                               int R, int C) {
  __shared__ float tile[32][33];
  const float* src = blockIdx.z ? s1 : s0;
  u16* dst = blockIdx.z ? d1 : d0;
  const int c0 = blockIdx.x * 32, r0 = blockIdx.y * 32;
  const int tx = threadIdx.x, ty = threadIdx.y;
#pragma unroll
  for (int i = 0; i < 4; ++i)
    tile[ty + i * 8][tx] = src[(size_t)(r0 + ty + i * 8) * C + c0 + tx];
  __syncthreads();
#pragma unroll
  for (int i = 0; i < 4; ++i)
    dst[(size_t)(c0 + ty + i * 8) * R + r0 + tx] = bfu(tile[tx][ty + i * 8]);
}

// ---------- fused RoPE(Q,K) + V-transpose from bf16 QKV (one dispatch) ----------
// bid < 4096: RoPE row (b*2048+t). bid >= 4096: V transpose tile.
__global__ __launch_bounds__(256) void rope_tv(const u16* __restrict__ QKV, const float* __restrict__ bq,
                                               const float* __restrict__ bk, const float* __restrict__ bv,
                                               u16* __restrict__ Qb, u16* __restrict__ Kb,
                                               u16* __restrict__ Vt) {
  const int bid = blockIdx.x;
  const int tid = threadIdx.x;
  if (bid < 4096) {
    const int row = bid;               // b*2048 + t
    const int b = row >> 11, t = row & 2047;
    const u16* qrow = QKV + (size_t)row * 2304;
    const float scale = 0.1275173862437171f;    // log2(e)/sqrt(128)
    const float nl2 = -0.20762050593046f;       // -log2(10000)/64
#pragma unroll
    for (int it = 0; it < 4; ++it) {
      int idx = tid + it * 256;        // 0..1023 : h*64 + j
      int h = idx >> 6, j = idx & 63;
      float q0 = b2f(qrow[h * 128 + j]) + bq[h * 128 + j];
      float q1 = b2f(qrow[h * 128 + j + 64]) + bq[h * 128 + j + 64];
      float ang = (float)t * exp2f((float)j * nl2);
      float s, c;
      __sincosf(ang, &s, &c);
      size_t o = ((size_t)((b * 16 + h) * 2048 + t)) * 128 + j;
      Qb[o]      = bfu((q0 * c - q1 * s) * scale);
      Qb[o + 64] = bfu((q1 * c + q0 * s) * scale);
    }
    if (tid < 64) {
      int j = tid;
      float k0 = b2f(qrow[2048 + j]) + bk[j];
      float k1 = b2f(qrow[2048 + j + 64]) + bk[j + 64];
      float ang = (float)t * exp2f((float)j * nl2);
      float s, c;
      __sincosf(ang, &s, &c);
      size_t o = (size_t)row * 128 + j;
      Kb[o]      = bfu(k0 * c - k1 * s);
      Kb[o + 64] = bfu(k1 * c + k0 * s);
    }
  } else {
    __shared__ float tile[32][33];
    const int idx = bid - 4096;        // 0..511
    const int b = idx >> 8, rem = idx & 255;
    const int t0 = (rem & 63) * 32, d0 = (rem >> 6) * 32;
    const int tx = tid & 31, ty = tid >> 5;
#pragma unroll
    for (int i = 0; i < 4; ++i)
      tile[ty + i * 8][tx] = b2f(QKV[(size_t)(b * 2048 + t0 + ty + i * 8) * 2304 + 2176 + d0 + tx]) + bv[d0 + tx];
    __syncthreads();
#pragma unroll
    for (int i = 0; i < 4; ++i)
      Vt[(size_t)b * 262144 + (size_t)(d0 + ty + i * 8) * 2048 + t0 + tx] = bfu(tile[tx][ty + i * 8]);
  }
}

// ---------- GEMM: C[M][N] = A[M][K](bf16) @ Bt[N][K](bf16)^T (+bias), fp32 or bf16 out ----------
// R15-validated: 128x128 tile, BK=64, 4 waves 2x2, rule-21 XOR-chunk swizzle,
// XCD-chunked block swizzle over NTL n-tiles.
template <bool BIAS, int NTL, bool OUT16>
__global__ __launch_bounds__(256) void gemm_bt(const u16* __restrict__ A, const u16* __restrict__ Bt,
                                               const float* __restrict__ bias, float* __restrict__ C,
                                               int M, int N, int K) {
  const int lin = blockIdx.x;
  const int xcd = lin & 7, idx = lin >> 3;
  constexpr int HALF = NTL / 2;                 // 9 or 8
  const int ly = idx / HALF, lx = idx - ly * HALF;   // ly 0..7
  const int my = (xcd >> 1) * 8 + ly;           // m-tile 0..31
  const int nx = (xcd & 1) * HALF + lx;         // n-tile 0..NTL-1
  const int n0 = nx * 128, m0 = my * 128;
  const int tid = threadIdx.x, lane = tid & 63;
  const int wid = tid >> 6, wr = wid >> 1, wc = wid & 1;
  __shared__ __align__(16) u16 As[128 * 64];    // 16 KB
  __shared__ __align__(16) u16 Bs[128 * 64];    // 16 KB
  f32x4 acc[4][4];
#pragma unroll
  for (int i = 0; i < 4; ++i)
#pragma unroll
    for (int j = 0; j < 4; ++j)
#pragma unroll
      for (int rr = 0; rr < 4; ++rr) acc[i][j][rr] = 0.f;

  // staging: thread covers 4 chunks (tile = 128 rows x 8 chunks of 16B = 1024 slots)
  int srow[4], scol[4];
#pragma unroll
  for (int i = 0; i < 4; ++i) {
    const int c = tid + i * 256;
    srow[i] = c >> 3;                                   // LDS row 0..127
    scol[i] = (((c & 7) ^ (srow[i] & 7)) << 3);         // swizzled source chunk (u16 units)
  }
  const int r = lane & 15, g = lane >> 4;
  // swizzled read offsets: row&7 == r&7 for all fragment rows
  int koff[2];
#pragma unroll
  for (int s = 0; s < 2; ++s) koff[s] = (((s * 4 + g) ^ (r & 7)) << 3);

  const int NT = K >> 6;                        // 32 K-steps of 64
  for (int t = 0; t < NT; ++t) {
    const int k0 = t << 6;
#pragma unroll
    for (int i = 0; i < 4; ++i)
      gl_lds16(A + (size_t)(m0 + srow[i]) * K + k0 + scol[i], As + (tid + i * 256) * 8);
#pragma unroll
    for (int i = 0; i < 4; ++i)
      gl_lds16(Bt + (size_t)(n0 + srow[i]) * K + k0 + scol[i], Bs + (tid + i * 256) * 8);
    __syncthreads();
#pragma unroll
    for (int s = 0; s < 2; ++s) {
      bf16x8 af[4], bfr[4];
#pragma unroll
      for (int mi = 0; mi < 4; ++mi)
        af[mi] = *reinterpret_cast<const bf16x8*>(&As[(wr * 64 + mi * 16 + r) * 64 + koff[s]]);
#pragma unroll
      for (int ni = 0; ni < 4; ++ni)
        bfr[ni] = *reinterpret_cast<const bf16x8*>(&Bs[(wc * 64 + ni * 16 + r) * 64 + koff[s]]);
#pragma unroll
      for (int mi = 0; mi < 4; ++mi)
#pragma unroll
        for (int ni = 0; ni < 4; ++ni)
          acc[mi][ni] = __builtin_amdgcn_mfma_f32_16x16x32_bf16(af[mi], bfr[ni], acc[mi][ni], 0, 0, 0);
    }
    __syncthreads();
  }
#pragma unroll
  for (int mi = 0; mi < 4; ++mi)
#pragma unroll
    for (int ni = 0; ni < 4; ++ni) {
      int col = n0 + wc * 64 + ni * 16 + r;
      float bia = BIAS ? bias[col] : 0.f;
#pragma unroll
      for (int reg = 0; reg < 4; ++reg) {
        int row = m0 + wr * 64 + mi * 16 + g * 4 + reg;
        if constexpr (OUT16) {
          ((u16*)C)[(size_t)row * N + col] = bfu(acc[mi][ni][reg] + bia);
        } else {
          C[(size_t)row * N + col] = acc[mi][ni][reg] + bia;
        }
      }
    }
}

// ---------- flash attention (causal, MQA), LDS-staged double-buffered K/V (R12-validated) ----------
__global__ __launch_bounds__(256, 2) void attn_kernel(const u16* __restrict__ Qb, const u16* __restrict__ Kb,
                                                      const u16* __restrict__ Vt, u16* __restrict__ Ob) {
  const int bid = blockIdx.x;
  const int grp = bid >> 5;                       // 0..15
  const int chunk = (bid < 256) ? (15 - grp) : (grp - 8);
  const int bh = bid & 31, h = bh & 15, b = bh >> 4;
  const int tid = threadIdx.x, wid = tid >> 6, lane = tid & 63;
  const int l31 = lane & 31, hf = lane >> 5;

  __shared__ __align__(16) u16 smem[32768];       // 64KB
  u16* Ksb = smem;                                // [2][8192]
  u16* Vsb = smem + 16384;                        // [2][8192]

  const u16* Kbase = Kb + (size_t)b * 2048 * 128;
  const u16* Vbase = Vt + (size_t)b * 128 * 2048;

  int krow[4], kcol[4], vrow[4], vcol[4];
#pragma unroll
  for (int i = 0; i < 4; ++i) {
    const int seg = wid * 4 + i;
    const int r = seg * 4 + (lane >> 4);                 // K tile row (kv)
    krow[i] = r; kcol[i] = (((lane & 15) ^ (r & 15)) << 3);
    const int d = seg * 8 + (lane >> 3);                 // V tile row (d)
    vrow[i] = d; vcol[i] = (((lane & 7) ^ (d & 7)) << 3);
  }
  const int ldsoff = wid * 2048 + lane * 8;              // u16 units

#define STAGE(buf, kvb_) do {                                                              \
    _Pragma("unroll") for (int i_ = 0; i_ < 4; ++i_)                                       \
      gl_lds16(Kbase + (size_t)((kvb_) + krow[i_]) * 128 + kcol[i_],                       \
               &Ksb[(buf) * 8192 + ldsoff + i_ * 512]);                                    \
    _Pragma("unroll") for (int i_ = 0; i_ < 4; ++i_)                                       \
      gl_lds16(Vbase + (size_t)vrow[i_] * 2048 + (kvb_) + vcol[i_],                        \
               &Vsb[(buf) * 8192 + ldsoff + i_ * 512]);                                    \
  } while (0)

  const int xk16 = l31 & 15;   // K read swizzle
  const int xk8 = l31 & 7;     // V read swizzle

  const int cb = chunk * 128;
  const int qw = cb + wid * 32;                          // this wave's q-tile base
  const u16* qptr = Qb + ((size_t)((b * 16 + h) * 2048 + qw + l31)) * 128;
  bf16x8 qf[8];
#pragma unroll
  for (int c = 0; c < 8; ++c)
    qf[c] = *reinterpret_cast<const bf16x8*>(qptr + c * 16 + hf * 8);

  f32x16 ot[4];
#pragma unroll
  for (int dt = 0; dt < 4; ++dt)
#pragma unroll
    for (int rr = 0; rr < 16; ++rr) ot[dt][rr] = 0.f;
  float m = -1e30f, lsum = 0.f;

  const int nkv = 2 * chunk + 2;
  STAGE(0, 0);
  for (int it = 0; it < nkv; ++it) {
    const int kvb = it << 6, cur = it & 1;
    if (it + 1 < nkv) {
      STAGE(cur ^ 1, kvb + 64);
      asm volatile("s_waitcnt vmcnt(8)" ::: "memory");
    } else {
      asm volatile("s_waitcnt vmcnt(0)" ::: "memory");
    }
    __builtin_amdgcn_s_barrier();

    if (kvb <= qw) {
      const u16* ks = Ksb + cur * 8192;
      const u16* vs = Vsb + cur * 8192;
      f32x16 st0, st1;
#pragma unroll
      for (int rr = 0; rr < 16; ++rr) { st0[rr] = 0.f; st1[rr] = -1e30f; }
      const u16* ksr0 = ks + l31 * 128;
#pragma unroll
      for (int c = 0; c < 8; ++c) {
        bf16x8 kf = *reinterpret_cast<const bf16x8*>(ksr0 + (((2 * c + hf) ^ xk16) << 3));
        st0 = __builtin_amdgcn_mfma_f32_32x32x16_bf16(kf, qf[c], st0, 0, 0, 0);
      }
      const bool a1 = (kvb + 32 <= qw);
      if (a1) {
#pragma unroll
        for (int rr = 0; rr < 16; ++rr) st1[rr] = 0.f;
        const u16* ksr1 = ks + (32 + l31) * 128;
#pragma unroll
        for (int c = 0; c < 8; ++c) {
          bf16x8 kf = *reinterpret_cast<const bf16x8*>(ksr1 + (((2 * c + hf) ^ xk16) << 3));
          st1 = __builtin_amdgcn_mfma_f32_32x32x16_bf16(kf, qf[c], st1, 0, 0, 0);
        }
        if (kvb + 32 == qw) {
#pragma unroll
          for (int rr = 0; rr < 16; ++rr) {
            int kvl = (rr & 3) + 8 * (rr >> 2) + 4 * hf;
            if (kvl > l31) st1[rr] = -1e30f;
          }
        }
      }
      if (kvb == qw) {
#pragma unroll
        for (int rr = 0; rr < 16; ++rr) {
          int kvl = (rr & 3) + 8 * (rr >> 2) + 4 * hf;
          if (kvl > l31) st0[rr] = -1e30f;
        }
      }

      float tmax = st0[0];
#pragma unroll
      for (int rr = 1; rr < 16; ++rr) tmax = fmaxf(tmax, st0[rr]);
#pragma unroll
      for (int rr = 0; rr < 16; ++rr) tmax = fmaxf(tmax, st1[rr]);
      tmax = fmaxf(tmax, __shfl_xor(tmax, 32, 64));
      if (!__all(tmax - m <= 8.f)) {
        const float mnew = fmaxf(m, tmax);
        const float alpha = exp2f(m - mnew);
        lsum *= alpha;
#pragma unroll
        for (int dt = 0; dt < 4; ++dt)
#pragma unroll
          for (int rr = 0; rr < 16; ++rr) ot[dt][rr] *= alpha;
        m = mnew;
      }
      float rsum = 0.f;
#pragma unroll
      for (int rr = 0; rr < 16; ++rr) { st0[rr] = exp2f(st0[rr] - m); rsum += st0[rr]; }
#pragma unroll
      for (int rr = 0; rr < 16; ++rr) { st1[rr] = exp2f(st1[rr] - m); rsum += st1[rr]; }
      rsum += __shfl_xor(rsum, 32, 64);
      lsum += rsum;

#pragma unroll
      for (int n = 0; n < 2; ++n) {
        if (n == 1 && !a1) break;
        const f32x16& pp = n ? st1 : st0;
#pragma unroll
        for (int s = 0; s < 2; ++s) {
          u32 a0p = pk2(pp[8 * s + 0], pp[8 * s + 1]);
          u32 a1p = pk2(pp[8 * s + 2], pp[8 * s + 3]);
          u32 b0p = pk2(pp[8 * s + 4], pp[8 * s + 5]);
          u32 b1p = pk2(pp[8 * s + 6], pp[8 * s + 7]);
          u32 k0 = hf ? b0p : a0p, k1 = hf ? b1p : a1p;
          u32 sd0 = hf ? a0p : b0p, sd1 = hf ? a1p : b1p;
          u32 r0 = (u32)__shfl_xor((int)sd0, 32, 64);
          u32 r1 = (u32)__shfl_xor((int)sd1, 32, 64);
          u32x4 pw;
          pw[0] = hf ? r0 : k0; pw[1] = hf ? r1 : k1;
          pw[2] = hf ? k0 : r0; pw[3] = hf ? k1 : r1;
          bf16x8 pb = __builtin_bit_cast(bf16x8, pw);
          const int cc = n * 4 + s * 2 + hf;
#pragma unroll
          for (int dt = 0; dt < 4; ++dt) {
            bf16x8 vf = *reinterpret_cast<const bf16x8*>(
                &vs[(dt * 32 + l31) * 64 + ((cc ^ xk8) << 3)]);
            ot[dt] = __builtin_amdgcn_mfma_f32_32x32x16_bf16(vf, pb, ot[dt], 0, 0, 0);
          }
        }
      }
    }
    __builtin_amdgcn_s_barrier();
  }

  // epilogue: normalize, LDS transpose (overlaid on K/V buffers), coalesced bf16 stores
  u16* myt = smem + wid * (32 * 136);
  const float inv = 1.f / lsum;
#pragma unroll
  for (int dt = 0; dt < 4; ++dt)
#pragma unroll
    for (int rq = 0; rq < 4; ++rq) {
      int d = dt * 32 + 8 * rq + 4 * hf;
      u32 lo = pk2(ot[dt][rq * 4 + 0] * inv, ot[dt][rq * 4 + 1] * inv);
      u32 hi = pk2(ot[dt][rq * 4 + 2] * inv, ot[dt][rq * 4 + 3] * inv);
      u32* dstp = (u32*)&myt[l31 * 136 + d];
      dstp[0] = lo; dstp[1] = hi;
    }
  __syncthreads();
  const size_t outbase = ((size_t)(b * 2048 + qw)) * 2048 + h * 128;
#pragma unroll
  for (int i = 0; i < 8; ++i) {
    int chunk2 = i * 64 + lane;
    int row = chunk2 >> 4, c16 = chunk2 & 15;
    u32x4 v = *reinterpret_cast<const u32x4*>(&myt[row * 136 + c16 * 8]);
    *reinterpret_cast<u32x4*>(Ob + outbase + (size_t)row * 2048 + c16 * 8) = v;
  }
#undef STAGE
}

// ---------- launch ----------
extern "C" void kernel_launch(void* const* d_in, const int* in_sizes, int n_in,
                              void* d_out, int out_size, void* d_ws, size_t ws_size,
                              hipStream_t stream) {
  const float* x  = (const float*)d_in[0];
  // d_in[1] = attn_mask (causal tril; applied analytically)
  const float* Wq = (const float*)d_in[2];
  const float* bq = (const float*)d_in[3];
  const float* Wk = (const float*)d_in[4];
  const float* bk = (const float*)d_in[5];
  const float* Wv = (const float*)d_in[6];
  const float* bv = (const float*)d_in[7];
  const float* Wo = (const float*)d_in[8];
  const float* bo = (const float*)d_in[9];

  char* ws = (char*)d_ws;
  u16*  xb    = (u16*)ws;   ws += (size_t)4096 * 2048 * 2;   // x bf16
  u16*  WqkvT = (u16*)ws;   ws += (size_t)2304 * 2048 * 2;   // [Wq|Wk|Wv]^T bf16
  u16*  WoT   = (u16*)ws;   ws += (size_t)2048 * 2048 * 2;   // Wo^T bf16
  u16*  QKV16 = (u16*)ws;   ws += (size_t)4096 * 2304 * 2;   // projections bf16
  u16*  Qb    = (u16*)ws;   ws += (size_t)2 * 16 * 2048 * 128 * 2; // [B,H,T,D] (RoPE'd, exp2-scaled)
  u16*  Kb    = (u16*)ws;   ws += (size_t)2 * 2048 * 128 * 2;      // [B,T,D] (RoPE'd)
  u16*  Vt    = (u16*)ws;   ws += (size_t)2 * 128 * 2048 * 2;      // [B,D,T]
  u16*  Ob    = (u16*)ws;   ws += (size_t)4096 * 2048 * 2;         // attn out bf16 [B*T][H*D]

  dim3 tb(32, 8);
  cvt_bf16<<<4096, 256, 0, stream>>>(x, xb, 1048576);
  transpose_cvt2<<<dim3(64, 64, 2), tb, 0, stream>>>(Wq, WqkvT, Wo, WoT, 2048, 2048);
  transpose_cvt2<<<dim3(4, 64, 2), tb, 0, stream>>>(Wk, WqkvT + (size_t)2048 * 2048,
                                                    Wv, WqkvT + (size_t)2176 * 2048, 2048, 128);

  gemm_bt<false, 18, true><<<576, 256, 0, stream>>>(xb, WqkvT, nullptr, (float*)QKV16, 4096, 2304, 2048);
  rope_tv<<<4608, 256, 0, stream>>>(QKV16, bq, bk, bv, Qb, Kb, Vt);
  attn_kernel<<<512, 256, 0, stream>>>(Qb, Kb, Vt, Ob);
  gemm_bt<true, 16, false><<<512, 256, 0, stream>>>(Ob, WoT, bo, (float*)d_out, 4096, 2048, 2048);
}